// Round 13
// baseline (226.533 us; speedup 1.0000x reference)
//
#include <hip/hip_runtime.h>

typedef unsigned short ushort_t;
typedef __attribute__((ext_vector_type(8))) short short8;
typedef __attribute__((ext_vector_type(8))) unsigned short ushort8;
typedef __attribute__((ext_vector_type(4))) unsigned short ushort4v;
typedef __attribute__((ext_vector_type(4))) float f32x4;
typedef __attribute__((ext_vector_type(4))) float float4v;

__device__ __forceinline__ float bf2f(ushort_t u) {
  return __uint_as_float(((unsigned)u) << 16);
}
__device__ __forceinline__ ushort_t f2bf(float f) {
  unsigned u = __float_as_uint(f);
  u += 0x7fffu + ((u >> 16) & 1u);   // RNE; inputs never NaN
  return (ushort_t)(u >> 16);
}

// async global->LDS, 16B per lane. LDS dest is wave-uniform base + lane*16.
__device__ __forceinline__ void gload16(ushort_t* lds, const ushort_t* g) {
  __builtin_amdgcn_global_load_lds(
      (const __attribute__((address_space(1))) unsigned int*)g,
      (__attribute__((address_space(3))) unsigned int*)lds, 16, 0, 0);
}

// ---------------- alpha = mean(|w|) + 1e-8 (two-stage, deterministic) ----------------
__global__ void k_abs_partial(const float* __restrict__ w1, const float* __restrict__ w2,
                              const float* __restrict__ w3, const float* __restrict__ w4,
                              float* __restrict__ apart) {
  int wy = blockIdx.y;
  const float* w; int n;
  if (wy == 0)      { w = w1; n = 1024 * 784; }
  else if (wy == 1) { w = w2; n = 512 * 1024; }
  else if (wy == 2) { w = w3; n = 256 * 512; }
  else              { w = w4; n = 10 * 256; }
  float s = 0.f;
  for (int i = blockIdx.x * 256 + threadIdx.x; i < n; i += 64 * 256)
    s += fabsf(w[i]);
  __shared__ float red[256];
  red[threadIdx.x] = s;
  __syncthreads();
  for (int st = 128; st > 0; st >>= 1) {
    if (threadIdx.x < st) red[threadIdx.x] += red[threadIdx.x + st];
    __syncthreads();
  }
  if (threadIdx.x == 0) apart[wy * 64 + blockIdx.x] = red[0];
}

__global__ void k_alpha_fin(const float* __restrict__ apart, float* __restrict__ alphas) {
  int wid = threadIdx.x >> 6, lane = threadIdx.x & 63;
  float v = apart[wid * 64 + lane];
  #pragma unroll
  for (int off = 32; off > 0; off >>= 1) v += __shfl_xor(v, off);
  if (lane == 0) {
    float inv;
    if (wid == 0)      inv = 1.f / (1024.f * 784.f);
    else if (wid == 1) inv = 1.f / (512.f * 1024.f);
    else if (wid == 2) inv = 1.f / (256.f * 512.f);
    else               inv = 1.f / 2560.f;
    alphas[wid] = v * inv + 1e-8f;
  }
}

// ---------------- ternary quantize -> bf16 {-1,0,1}, alpha factored out ----------------
__global__ void k_quantize(const float* __restrict__ w1, const float* __restrict__ w2,
                           const float* __restrict__ w3, const float* __restrict__ w4,
                           ushort_t* __restrict__ q1, ushort_t* __restrict__ q2,
                           ushort_t* __restrict__ q3, ushort_t* __restrict__ q4,
                           const float* __restrict__ alphas) {
  int wy = blockIdx.y;
  const float* w; ushort_t* q; int R, K, Kp;
  if (wy == 0)      { w = w1; q = q1; R = 1024; K = 784;  Kp = 832;  }
  else if (wy == 1) { w = w2; q = q2; R = 512;  K = 1024; Kp = 1024; }
  else if (wy == 2) { w = w3; q = q3; R = 256;  K = 512;  Kp = 512;  }
  else              { w = w4; q = q4; R = 10;   K = 256;  Kp = 256;  }
  float a = alphas[wy];
  int total = R * Kp;
  for (int i = blockIdx.x * 256 + threadIdx.x; i < total; i += gridDim.x * 256) {
    int r = i / Kp, k = i - r * Kp;
    float v = 0.f;
    if (k < K) {
      float t = rintf(w[r * K + k] / a);   // rintf = RNE, matches jnp.round
      v = fminf(1.f, fmaxf(-1.f, t));
    }
    q[i] = f2bf(v);   // exact for {-1,0,1}
  }
}

// ---------------- x (f32, 32768x784) -> bf16 padded to 832 ----------------
__global__ void k_convert_x(const float* __restrict__ x, ushort_t* __restrict__ xq) {
  int idx = blockIdx.x * 256 + threadIdx.x;   // 32768*104 threads, 8 elems each
  int r = idx / 104;
  int c8 = idx - r * 104;
  int k0 = c8 << 3;
  ushort8 o;
  if (k0 < 784) {   // 784 % 8 == 0, so full chunks only
    const float4v* p = (const float4v*)(x + (size_t)r * 784 + k0);
    float4v v0 = p[0], v1 = p[1];
    o[0] = f2bf(v0[0]); o[1] = f2bf(v0[1]); o[2] = f2bf(v0[2]); o[3] = f2bf(v0[3]);
    o[4] = f2bf(v1[0]); o[5] = f2bf(v1[1]); o[6] = f2bf(v1[2]); o[7] = f2bf(v1[3]);
  } else {
    #pragma unroll
    for (int j = 0; j < 8; ++j) o[j] = 0;
  }
  *(ushort8*)(xq + (size_t)r * 832 + k0) = o;
}

// ===== 256x256-tile, 8-wave bf16 MFMA GEMM: m201-style 4-phase counted pipeline =====
// C_bf16 = alpha*(A @ B^T) + transposed BN partial stats psum/psq[col][256].
// R13: faithful template port. Per tile t, 4 phases, each
//   {ds_read subtile ; stage 1 half-tile (2 gload_lds) ; barrier ;
//    lgkmcnt(0)+sched_barrier ; setprio(1) 16 MFMA setprio(0) ; barrier}
// Quadrants: ph1=(mh0,nh0) ph2=(mh0,nh1) ph3=(mh1,nh1) ph4=(mh1,nh0; no reads).
// Staging classes: ph1/ph2 stage t+1's A-halves into NXT (nxt fully consumed at
// t-1: unconstrained); ph3/ph4 stage t+2's B-halves into CUR ((t+2)&1==t&1; B
// regions' last read is ph2, globally closed by ph2's post-MFMA barrier).
// FIFO wait ledger (per wave): entering tile t: 4 outstanding (t+1.B from t-1's
// ph3/4). Issues during t: +8. Boundary at ph4 waits vmcnt(4): confirms ALL of
// t+1 (B staged ~5 phases ago, A 2-3 phases ago, both >= HBM latency ~900cy);
// leaves t+2.B0,B1 in flight -- the loop NEVER drains vmcnt to 0. Tail: vmcnt(0)
// when t+2>=nk (remaining loads are old; free). Prologue: t0 all 4 halves +
// t1.B0,B1, wait vmcnt(4). Race audit: every stage targets a region whose last
// ds_read was globally closed >=1 barrier earlier; all waves pass the boundary
// vmcnt before the barrier that releases next-tile reads.
// LDS XOR-swizzle byte^=((row&7)<<4) via inverse-swizzled per-lane GLOBAL source
// + swizzled ds_read (linear DMA dest: rule-21-correct). Bank conflicts = 0 (R6).
__global__ __launch_bounds__(512, 2) void k_gemm256(
    const ushort_t* __restrict__ A, const ushort_t* __restrict__ Bw,
    ushort_t* __restrict__ C, const float* __restrict__ alphas, int layer,
    float* __restrict__ psum, float* __restrict__ psq,
    int N, int K, int nbxl) {
  __shared__ char smem[131072];   // [A0|A1|B0|B1], 32KB each
  const int tid = threadIdx.x;
  const int lane = tid & 63;
  const int wid = tid >> 6;
  const int wr = wid >> 2, wc = wid & 3;
  const int l15 = lane & 15, l4 = lane >> 4;
  const int swz = (lane & 7) << 4;            // read-side XOR (row&7)<<4, row&7==lane&7

  const int cpx = gridDim.x >> 3;             // bijective XCD swizzle (nwg%8==0)
  const int orig = (blockIdx.x & 7) * cpx + (blockIdx.x >> 3);
  const int colt = orig & ((1 << nbxl) - 1);
  const int rowt = orig >> nbxl;
  const int row0 = rowt << 8, col0 = colt << 8;

  f32x4 acc[8][4];
  #pragma unroll
  for (int m = 0; m < 8; ++m)
    #pragma unroll
    for (int n = 0; n < 4; ++n) acc[m][n] = (f32x4){0.f, 0.f, 0.f, 0.f};

  // staging geometry: wave wid covers 8-row stripes; half-tile = 128 rows (16KB)
  const int srow8 = wid * 8 + (lane >> 3);            // 0..63
  const int csw = ((lane & 7) ^ (lane >> 3)) << 3;    // inverse-swizzled k-chunk (elems)
  const ushort_t* Ag = A + (size_t)(row0 + srow8) * K + csw;
  const ushort_t* Bg = Bw + (size_t)(col0 + srow8) * K + csw;

  // stage A half h of K-tile kt into buffer nx: rows [h*128, h*128+128)
  auto stageA_h = [&](int kt, int nx, int h) {
    char* dst = smem + (nx << 15) + h * 16384 + (wid << 10);
    const ushort_t* src = Ag + (size_t)(h * 128) * K + kt * 64;
    gload16((ushort_t*)dst, src);
    gload16((ushort_t*)(dst + 8192), src + (size_t)64 * K);
  };
  auto stageB_h = [&](int kt, int nx, int h) {
    char* dst = smem + 65536 + (nx << 15) + h * 16384 + (wid << 10);
    const ushort_t* src = Bg + (size_t)(h * 128) * K + kt * 64;
    gload16((ushort_t*)dst, src);
    gload16((ushort_t*)(dst + 8192), src + (size_t)64 * K);
  };

  short8 a[8], b0[4], b1[4];
  auto lda_ks = [&](int cur, int mh, int ks) {
    const char* Ab = smem + (cur << 15);
    #pragma unroll
    for (int mm = 0; mm < 4; ++mm) {
      int ar = wr * 128 + (mh * 4 + mm) * 16 + l15;
      a[ks * 4 + mm] = *(const short8*)(Ab + ar * 128 + ((ks * 64 + l4 * 16) ^ swz));
    }
  };
  auto ldb_ks = [&](short8* bb, int cur, int nh, int ks) {
    const char* Bb = smem + 65536 + (cur << 15);
    #pragma unroll
    for (int nn = 0; nn < 2; ++nn) {
      int br = wc * 64 + (nh * 2 + nn) * 16 + l15;
      bb[ks * 2 + nn] = *(const short8*)(Bb + br * 128 + ((ks * 64 + l4 * 16) ^ swz));
    }
  };
  auto mfma16 = [&](int mh, int nh, const short8* bb) {
    __builtin_amdgcn_s_setprio(1);
    #pragma unroll
    for (int ks = 0; ks < 2; ++ks)
      #pragma unroll
      for (int mm = 0; mm < 4; ++mm)
        #pragma unroll
        for (int nn = 0; nn < 2; ++nn)
          acc[mh * 4 + mm][nh * 2 + nn] = __builtin_amdgcn_mfma_f32_16x16x32_bf16(
              a[ks * 4 + mm], bb[ks * 2 + nn], acc[mh * 4 + mm][nh * 2 + nn], 0, 0, 0);
    __builtin_amdgcn_s_setprio(0);
  };

  const int nk = K >> 6;

  // prologue: tile0 all 4 halves (buf0) + tile1's B halves (buf1); wait tile0 only
  stageA_h(0, 0, 0);
  stageA_h(0, 0, 1);
  stageB_h(0, 0, 0);
  stageB_h(0, 0, 1);
  if (nk > 1) {
    stageB_h(1, 1, 0);
    stageB_h(1, 1, 1);
    asm volatile("s_waitcnt vmcnt(4)" ::: "memory");   // t0's 8 confirmed; t1.B in flight
  } else {
    asm volatile("s_waitcnt vmcnt(0)" ::: "memory");
  }
  __builtin_amdgcn_s_barrier();
  __builtin_amdgcn_sched_barrier(0);

  for (int t = 0; t < nk; ++t) {
    const int cur = t & 1, nxt = cur ^ 1;
    const bool pA = (t + 1 < nk);   // stage t+1's A halves into nxt
    const bool pB = (t + 2 < nk);   // stage t+2's B halves into cur
    // ph1: (mh0,nh0). reads a[mh0] ks0+ks1 (8) + b0[nh0] (4); stage t+1.A-h0
    lda_ks(cur, 0, 0);
    ldb_ks(b0, cur, 0, 0);
    lda_ks(cur, 0, 1);
    ldb_ks(b0, cur, 0, 1);
    if (pA) stageA_h(t + 1, nxt, 0);
    __builtin_amdgcn_s_barrier();
    asm volatile("s_waitcnt lgkmcnt(0)" ::: "memory");
    __builtin_amdgcn_sched_barrier(0);
    mfma16(0, 0, b0);
    __builtin_amdgcn_s_barrier();
    // ph2: (mh0,nh1). reads b1[nh1] (4); stage t+1.A-h1
    ldb_ks(b1, cur, 1, 0);
    ldb_ks(b1, cur, 1, 1);
    if (pA) stageA_h(t + 1, nxt, 1);
    __builtin_amdgcn_s_barrier();
    asm volatile("s_waitcnt lgkmcnt(0)" ::: "memory");
    __builtin_amdgcn_sched_barrier(0);
    mfma16(0, 1, b1);
    __builtin_amdgcn_s_barrier();
    // ph3: (mh1,nh1). reads a[mh1] (8); stage t+2.B-h0 into cur (B last read ph2)
    lda_ks(cur, 1, 0);
    lda_ks(cur, 1, 1);
    if (pB) stageB_h(t + 2, cur, 0);
    __builtin_amdgcn_s_barrier();
    asm volatile("s_waitcnt lgkmcnt(0)" ::: "memory");
    __builtin_amdgcn_sched_barrier(0);
    mfma16(1, 1, b1);
    __builtin_amdgcn_s_barrier();
    // ph4: (mh1,nh0). no reads; stage t+2.B-h1; counted boundary wait
    if (pB) stageB_h(t + 2, cur, 1);
    __builtin_amdgcn_s_barrier();
    mfma16(1, 0, b0);
    if (pB) {
      asm volatile("s_waitcnt vmcnt(4)" ::: "memory");  // confirm ALL of t+1; t+2.B in flight
    } else {
      asm volatile("s_waitcnt vmcnt(0)" ::: "memory");  // tail: remaining loads are old
    }
    __builtin_amdgcn_s_barrier();
    __builtin_amdgcn_sched_barrier(0);
  }

  // epilogue: store bf16 C + per-column partial stats (transposed [col][256])
  const float alpha = alphas[layer];
  float csum[4], csq[4];
  #pragma unroll
  for (int n = 0; n < 4; ++n) { csum[n] = 0.f; csq[n] = 0.f; }
  #pragma unroll
  for (int m = 0; m < 8; ++m) {
    const int rbase = row0 + wr * 128 + m * 16 + l4 * 4;
    #pragma unroll
    for (int n = 0; n < 4; ++n) {
      const int col = col0 + wc * 64 + n * 16 + l15;
      #pragma unroll
      for (int r = 0; r < 4; ++r) {
        ushort_t ub = f2bf(acc[m][n][r] * alpha);
        C[(size_t)(rbase + r) * N + col] = ub;
        float vv = bf2f(ub);
        csum[n] += vv;
        csq[n] += vv * vv;
      }
    }
  }
  #pragma unroll
  for (int n = 0; n < 4; ++n) {
    csum[n] += __shfl_xor(csum[n], 16);
    csum[n] += __shfl_xor(csum[n], 32);
    csq[n]  += __shfl_xor(csq[n], 16);
    csq[n]  += __shfl_xor(csq[n], 32);
  }
  if (l4 == 0) {
    const int prow = rowt * 2 + wr;      // 256 partials per column
    #pragma unroll
    for (int n = 0; n < 4; ++n) {
      const int col = col0 + wc * 64 + n * 16 + l15;
      psum[(size_t)col * 256 + prow] = csum[n];
      psq [(size_t)col * 256 + prow] = csq[n];
    }
  }
}

// ---------------- 128x128-tile GEMM (layer 3: N=256 keeps full-chip grid) -----------
__global__ __launch_bounds__(256, 3) void k_gemm_bt(
    const ushort_t* __restrict__ A, const ushort_t* __restrict__ Bw,
    ushort_t* __restrict__ C, const float* __restrict__ alphas, int layer,
    float* __restrict__ psum, float* __restrict__ psq,
    int N, int K, int nbxl) {
  __shared__ ushort_t As[8192];   // [128][64] linear
  __shared__ ushort_t Bs[8192];
  const int tid = threadIdx.x;
  const int lane = tid & 63;
  const int wv = tid >> 6;
  const int wr = (tid >> 7) & 1;
  const int wc = (tid >> 6) & 1;
  const int l15 = lane & 15, l4 = lane >> 4;

  const int cpx = gridDim.x >> 3;
  const int orig = (blockIdx.x & 7) * cpx + (blockIdx.x >> 3);
  const int colt = orig & ((1 << nbxl) - 1);
  const int rowt = orig >> nbxl;
  const int row0 = rowt << 7, col0 = colt << 7;

  f32x4 acc[4][4];
  #pragma unroll
  for (int m = 0; m < 4; ++m)
    #pragma unroll
    for (int n = 0; n < 4; ++n) acc[m][n] = (f32x4){0.f, 0.f, 0.f, 0.f};

  const int srow = lane >> 3;
  const int sk = (lane & 7) << 3;
  const ushort_t* Ag = A + (size_t)(row0 + wv * 32 + srow) * K + sk;
  const ushort_t* Bg = Bw + (size_t)(col0 + wv * 32 + srow) * K + sk;
  ushort_t* Asw = As + wv * 32 * 64;
  ushort_t* Bsw = Bs + wv * 32 * 64;
  const size_t r8 = (size_t)8 * K;

  const int nk = K >> 6;
  for (int kt = 0; kt < nk; ++kt) {
    __syncthreads();
    const ushort_t* Agk = Ag + kt * 64;
    const ushort_t* Bgk = Bg + kt * 64;
    #pragma unroll
    for (int c = 0; c < 4; ++c) {
      gload16(Asw + c * 512, Agk + c * r8);
      gload16(Bsw + c * 512, Bgk + c * r8);
    }
    __syncthreads();
    #pragma unroll
    for (int ks = 0; ks < 2; ++ks) {
      short8 af[4], bfv[4];
      #pragma unroll
      for (int m = 0; m < 4; ++m)
        af[m] = *(const short8*)(As + (wr * 64 + m * 16 + l15) * 64 + ks * 32 + l4 * 8);
      #pragma unroll
      for (int n = 0; n < 4; ++n)
        bfv[n] = *(const short8*)(Bs + (wc * 64 + n * 16 + l15) * 64 + ks * 32 + l4 * 8);
      #pragma unroll
      for (int m = 0; m < 4; ++m)
        #pragma unroll
        for (int n = 0; n < 4; ++n)
          acc[m][n] = __builtin_amdgcn_mfma_f32_16x16x32_bf16(af[m], bfv[n], acc[m][n], 0, 0, 0);
    }
  }

  const float alpha = alphas[layer];
  float csum[4], csq[4];
  #pragma unroll
  for (int n = 0; n < 4; ++n) { csum[n] = 0.f; csq[n] = 0.f; }
  #pragma unroll
  for (int m = 0; m < 4; ++m) {
    const int rbase = row0 + wr * 64 + m * 16 + l4 * 4;
    #pragma unroll
    for (int n = 0; n < 4; ++n) {
      const int col = col0 + wc * 64 + n * 16 + l15;
      #pragma unroll
      for (int r = 0; r < 4; ++r) {
        ushort_t ub = f2bf(acc[m][n][r] * alpha);
        C[(size_t)(rbase + r) * N + col] = ub;
        float vv = bf2f(ub);
        csum[n] += vv;
        csq[n] += vv * vv;
      }
    }
  }
  #pragma unroll
  for (int n = 0; n < 4; ++n) {
    csum[n] += __shfl_xor(csum[n], 16);
    csum[n] += __shfl_xor(csum[n], 32);
    csq[n]  += __shfl_xor(csq[n], 16);
    csq[n]  += __shfl_xor(csq[n], 32);
  }
  if (l4 == 0) {
    const int prow = rowt * 2 + wr;      // 512 partials per column
    #pragma unroll
    for (int n = 0; n < 4; ++n) {
      const int col = col0 + wc * 64 + n * 16 + l15;
      psum[(size_t)col * 512 + prow] = csum[n];
      psq [(size_t)col * 512 + prow] = csq[n];
    }
  }
}

// ------- fold BN: S = g/sqrt(var+eps), B = b - mean*S. One wave per feature. -------
// psum/psq are [N][P]; coalesced float4 loads + 64-lane shuffle tree. Grid = N/4.
__global__ void k_bn_fin(const float* __restrict__ psum, const float* __restrict__ psq,
                         const float* __restrict__ g, const float* __restrict__ bb,
                         int N, int P, float* __restrict__ SB) {
  int lane = threadIdx.x & 63;
  int f = blockIdx.x * 4 + (threadIdx.x >> 6);
  const float4v* ps = (const float4v*)(psum + (size_t)f * P);
  const float4v* pq = (const float4v*)(psq  + (size_t)f * P);
  float s = 0.f, q = 0.f;
  for (int i = lane; i < (P >> 2); i += 64) {
    float4v a = ps[i], c = pq[i];
    s += (a[0] + a[1]) + (a[2] + a[3]);
    q += (c[0] + c[1]) + (c[2] + c[3]);
  }
  #pragma unroll
  for (int off = 32; off > 0; off >>= 1) {
    s += __shfl_xor(s, off);
    q += __shfl_xor(q, off);
  }
  if (lane == 0) {
    float mean = s * (1.f / 32768.f);
    float var  = q * (1.f / 32768.f) - mean * mean;   // biased, matches torch/jnp
    float Sv = g[f] / sqrtf(var + 1e-5f);
    SB[f] = Sv;
    SB[N + f] = bb[f] - mean * Sv;
  }
}

// ---------------- in-place normalize + ReLU (bf16) ----------------
__global__ void k_bn_norm(ushort_t* __restrict__ Y, const float* __restrict__ SB, int N) {
  size_t e0 = ((size_t)blockIdx.x * 256 + threadIdx.x) * 8;
  int f0 = (int)(e0 & (size_t)(N - 1));
  ushort8 v = *(const ushort8*)(Y + e0);
  const float4v* Sp = (const float4v*)(SB + f0);
  const float4v* Bp = (const float4v*)(SB + N + f0);
  float4v S0 = Sp[0], S1 = Sp[1], B0 = Bp[0], B1 = Bp[1];
  ushort8 o;
  #pragma unroll
  for (int j = 0; j < 4; ++j) {
    float h = fmaxf(bf2f(v[j]) * S0[j] + B0[j], 0.f);
    o[j] = f2bf(h);
  }
  #pragma unroll
  for (int j = 0; j < 4; ++j) {
    float h = fmaxf(bf2f(v[4 + j]) * S1[j] + B1[j], 0.f);
    o[4 + j] = f2bf(h);
  }
  *(ushort8*)(Y + e0) = o;
}

// -------- final layer: out = alpha4 * (relu(bn3(y3)) @ t4^T); norm3 fused in --------
__global__ void k_final(const ushort_t* __restrict__ H, const ushort_t* __restrict__ W4,
                        const float* __restrict__ alphas, const float* __restrict__ SB,
                        float* __restrict__ out) {
  int lane = threadIdx.x & 63, wid = threadIdx.x >> 6;
  int row = blockIdx.x * 4 + wid;
  float a4 = alphas[3];
  ushort4v hv = *(const ushort4v*)(H + (size_t)row * 256 + lane * 4);
  float4v S = *(const float4v*)(SB + lane * 4);
  float4v Bv = *(const float4v*)(SB + 256 + lane * 4);
  float hf[4];
  #pragma unroll
  for (int j = 0; j < 4; ++j)
    hf[j] = fmaxf(bf2f(hv[j]) * S[j] + Bv[j], 0.f);   // BN3 + ReLU fused
  float acc[10];
  #pragma unroll
  for (int c = 0; c < 10; ++c) {
    ushort4v wv = *(const ushort4v*)(W4 + c * 256 + lane * 4);
    acc[c] = hf[0] * bf2f(wv[0]) + hf[1] * bf2f(wv[1]) +
             hf[2] * bf2f(wv[2]) + hf[3] * bf2f(wv[3]);
  }
  #pragma unroll
  for (int c = 0; c < 10; ++c) {
    #pragma unroll
    for (int off = 32; off > 0; off >>= 1) acc[c] += __shfl_xor(acc[c], off);
  }
  if (lane < 10) {
    float v = 0.f;
    #pragma unroll
    for (int c = 0; c < 10; ++c)
      if (lane == c) v = acc[c];
    out[(size_t)row * 10 + lane] = v * a4;
  }
}

// =====================================================================================
extern "C" void kernel_launch(void* const* d_in, const int* in_sizes, int n_in,
                              void* d_out, int out_size, void* d_ws, size_t ws_size,
                              hipStream_t stream) {
  const float* x  = (const float*)d_in[0];
  const float* w1 = (const float*)d_in[1];
  const float* w2 = (const float*)d_in[2];
  const float* w3 = (const float*)d_in[3];
  const float* w4 = (const float*)d_in[4];
  const float* g1 = (const float*)d_in[5];
  const float* b1 = (const float*)d_in[6];
  const float* g2 = (const float*)d_in[7];
  const float* b2 = (const float*)d_in[8];
  const float* g3 = (const float*)d_in[9];
  const float* b3 = (const float*)d_in[10];
  float* out = (float*)d_out;

  // workspace layout (~130 MB, all offsets 256B-aligned; xq aliased for y2)
  char* ws = (char*)d_ws;
  float* alphas   = (float*)(ws + 0);
  float* apart    = (float*)(ws + 256);
  float* SB1      = (float*)(ws + 4096);                 // 2*1024 f32
  float* SB2      = (float*)(ws + 16384);                // 2*512 f32
  float* SB3      = (float*)(ws + 24576);                // 2*256 f32
  float* psum     = (float*)(ws + 32768);                // [N<=1024][<=512] f32 (2 MB)
  float* psq      = (float*)(ws + 2129920);              // 2 MB
  ushort_t* wq1   = (ushort_t*)(ws + 4227072);           // 1024x832
  ushort_t* wq2   = (ushort_t*)(ws + 5931008);           // 512x1024
  ushort_t* wq3   = (ushort_t*)(ws + 6979584);           // 256x512
  ushort_t* wq4   = (ushort_t*)(ws + 7241728);           // 10x256
  ushort_t* xq    = (ushort_t*)(ws + 7246848);           // 32768x832 (54.5 MB)
  ushort_t* y2    = xq;                                  // alias: xq dead after GEMM1
  ushort_t* y3    = (ushort_t*)(ws + 7246848 + 54525952);  // 32768x256 (16.8 MB)
  ushort_t* y1    = (ushort_t*)(ws + 78643200);          // 32768x1024 (67 MB)

  dim3 blk(256);

  k_abs_partial<<<dim3(64, 4), blk, 0, stream>>>(w1, w2, w3, w4, apart);
  k_alpha_fin<<<1, blk, 0, stream>>>(apart, alphas);
  k_quantize<<<dim3(512, 4), blk, 0, stream>>>(w1, w2, w3, w4, wq1, wq2, wq3, wq4, alphas);
  k_convert_x<<<13312, blk, 0, stream>>>(x, xq);

  // layer 1: 32768 x 1024, K = 832; 256^2 tiles -> 128x4 = 512 blocks (nbxl=2)
  k_gemm256<<<512, 512, 0, stream>>>(xq, wq1, y1, alphas, 0, psum, psq, 1024, 832, 2);
  k_bn_fin<<<256, blk, 0, stream>>>(psum, psq, g1, b1, 1024, 256, SB1);
  k_bn_norm<<<16384, blk, 0, stream>>>(y1, SB1, 1024);

  // layer 2: 32768 x 512, K = 1024; 128x2 = 256 blocks (nbxl=1)
  k_gemm256<<<256, 512, 0, stream>>>(y1, wq2, y2, alphas, 1, psum, psq, 512, 1024, 1);
  k_bn_fin<<<128, blk, 0, stream>>>(psum, psq, g2, b2, 512, 256, SB2);
  k_bn_norm<<<8192, blk, 0, stream>>>(y2, SB2, 512);

  // layer 3: 32768 x 256, K = 512; keep 128^2 kernel (512 blocks, full chip)
  k_gemm_bt<<<512, blk, 0, stream>>>(y2, wq3, y3, alphas, 2, psum, psq, 256, 512, 1);
  k_bn_fin<<<64, blk, 0, stream>>>(psum, psq, g3, b3, 256, 512, SB3);
  // layer-3 normalize+ReLU fused into k_final

  // layer 4: 32768 x 10, K = 256 (memory-bound GEMV, BN3+ReLU fused)
  k_final<<<8192, blk, 0, stream>>>(y3, wq4, alphas, SB3, out);
}

// Round 14
// 215.618 us; speedup vs baseline: 1.0506x; 1.0506x over previous
//
#include <hip/hip_runtime.h>

typedef unsigned short ushort_t;
typedef __attribute__((ext_vector_type(8))) short short8;
typedef __attribute__((ext_vector_type(8))) unsigned short ushort8;
typedef __attribute__((ext_vector_type(4))) unsigned short ushort4v;
typedef __attribute__((ext_vector_type(4))) float f32x4;
typedef __attribute__((ext_vector_type(4))) float float4v;

__device__ __forceinline__ float bf2f(ushort_t u) {
  return __uint_as_float(((unsigned)u) << 16);
}
__device__ __forceinline__ ushort_t f2bf(float f) {
  unsigned u = __float_as_uint(f);
  u += 0x7fffu + ((u >> 16) & 1u);   // RNE; inputs never NaN
  return (ushort_t)(u >> 16);
}

// async global->LDS, 16B per lane. LDS dest is wave-uniform base + lane*16.
__device__ __forceinline__ void gload16(ushort_t* lds, const ushort_t* g) {
  __builtin_amdgcn_global_load_lds(
      (const __attribute__((address_space(1))) unsigned int*)g,
      (__attribute__((address_space(3))) unsigned int*)lds, 16, 0, 0);
}

// ---------------- alpha = mean(|w|) + 1e-8 (two-stage, deterministic) ----------------
__global__ void k_abs_partial(const float* __restrict__ w1, const float* __restrict__ w2,
                              const float* __restrict__ w3, const float* __restrict__ w4,
                              float* __restrict__ apart) {
  int wy = blockIdx.y;
  const float* w; int n;
  if (wy == 0)      { w = w1; n = 1024 * 784; }
  else if (wy == 1) { w = w2; n = 512 * 1024; }
  else if (wy == 2) { w = w3; n = 256 * 512; }
  else              { w = w4; n = 10 * 256; }
  float s = 0.f;
  for (int i = blockIdx.x * 256 + threadIdx.x; i < n; i += 64 * 256)
    s += fabsf(w[i]);
  __shared__ float red[256];
  red[threadIdx.x] = s;
  __syncthreads();
  for (int st = 128; st > 0; st >>= 1) {
    if (threadIdx.x < st) red[threadIdx.x] += red[threadIdx.x + st];
    __syncthreads();
  }
  if (threadIdx.x == 0) apart[wy * 64 + blockIdx.x] = red[0];
}

__global__ void k_alpha_fin(const float* __restrict__ apart, float* __restrict__ alphas) {
  int wid = threadIdx.x >> 6, lane = threadIdx.x & 63;
  float v = apart[wid * 64 + lane];
  #pragma unroll
  for (int off = 32; off > 0; off >>= 1) v += __shfl_xor(v, off);
  if (lane == 0) {
    float inv;
    if (wid == 0)      inv = 1.f / (1024.f * 784.f);
    else if (wid == 1) inv = 1.f / (512.f * 1024.f);
    else if (wid == 2) inv = 1.f / (256.f * 512.f);
    else               inv = 1.f / 2560.f;
    alphas[wid] = v * inv + 1e-8f;
  }
}

// ---------------- ternary quantize -> bf16 {-1,0,1}, alpha factored out ----------------
__global__ void k_quantize(const float* __restrict__ w1, const float* __restrict__ w2,
                           const float* __restrict__ w3, const float* __restrict__ w4,
                           ushort_t* __restrict__ q1, ushort_t* __restrict__ q2,
                           ushort_t* __restrict__ q3, ushort_t* __restrict__ q4,
                           const float* __restrict__ alphas) {
  int wy = blockIdx.y;
  const float* w; ushort_t* q; int R, K, Kp;
  if (wy == 0)      { w = w1; q = q1; R = 1024; K = 784;  Kp = 832;  }
  else if (wy == 1) { w = w2; q = q2; R = 512;  K = 1024; Kp = 1024; }
  else if (wy == 2) { w = w3; q = q3; R = 256;  K = 512;  Kp = 512;  }
  else              { w = w4; q = q4; R = 10;   K = 256;  Kp = 256;  }
  float a = alphas[wy];
  int total = R * Kp;
  for (int i = blockIdx.x * 256 + threadIdx.x; i < total; i += gridDim.x * 256) {
    int r = i / Kp, k = i - r * Kp;
    float v = 0.f;
    if (k < K) {
      float t = rintf(w[r * K + k] / a);   // rintf = RNE, matches jnp.round
      v = fminf(1.f, fmaxf(-1.f, t));
    }
    q[i] = f2bf(v);   // exact for {-1,0,1}
  }
}

// ---------------- x (f32, 32768x784) -> bf16 padded to 832 ----------------
__global__ void k_convert_x(const float* __restrict__ x, ushort_t* __restrict__ xq) {
  int idx = blockIdx.x * 256 + threadIdx.x;   // 32768*104 threads, 8 elems each
  int r = idx / 104;
  int c8 = idx - r * 104;
  int k0 = c8 << 3;
  ushort8 o;
  if (k0 < 784) {   // 784 % 8 == 0, so full chunks only
    const float4v* p = (const float4v*)(x + (size_t)r * 784 + k0);
    float4v v0 = p[0], v1 = p[1];
    o[0] = f2bf(v0[0]); o[1] = f2bf(v0[1]); o[2] = f2bf(v0[2]); o[3] = f2bf(v0[3]);
    o[4] = f2bf(v1[0]); o[5] = f2bf(v1[1]); o[6] = f2bf(v1[2]); o[7] = f2bf(v1[3]);
  } else {
    #pragma unroll
    for (int j = 0; j < 8; ++j) o[j] = 0;
  }
  *(ushort8*)(xq + (size_t)r * 832 + k0) = o;
}

// ============ 256x256-tile, 8-wave bf16 MFMA GEMM (R7 schedule, ks-split reads) =====
// SESSION-OPTIMAL configuration (R10/R12: GEMM1 62.4us, MfmaUtil ~35%, conflicts 0).
// C_bf16 = alpha*(A @ B^T) + transposed BN partial stats psum/psq[col][256].
// BK=64; LDS = 2 dbuf x (A 32KB + B 32KB) = 128KB; 512 threads = 8 waves (2Mx4N);
// per-wave output 128x64, 64 MFMA/K-tile.
// Schedule: per tile, 3 read-phases each ending in one barrier + MFMA cluster(s),
// then boundary vmcnt(0)+barrier. Falsified alternatives on THESE shapes (short
// K: nk=13/16, grid = 2 rounds/CU, 1 block/CU): 2-barrier/phase (R6) -7%;
// counted-vmcnt whole-tile (R8) -7%; counted-vmcnt half-tile ledger (R11) -5%;
// faithful 4-phase m201-style port (R13) -10%; in-staging fusion at 128^2 (R3)
// and 256^2 (R9) large regressions. Drain-at-boundary 3-phase is the measured
// optimum of the family at short K.
// LDS XOR-swizzle byte^=((row&7)<<4) via inverse-swizzled per-lane GLOBAL source
// + swizzled ds_read (linear DMA dest: rule-21-correct). Bank conflicts = 0 (R6).
__global__ __launch_bounds__(512, 2) void k_gemm256(
    const ushort_t* __restrict__ A, const ushort_t* __restrict__ Bw,
    ushort_t* __restrict__ C, const float* __restrict__ alphas, int layer,
    float* __restrict__ psum, float* __restrict__ psq,
    int N, int K, int nbxl) {
  __shared__ char smem[131072];   // [A0|A1|B0|B1], 32KB each
  const int tid = threadIdx.x;
  const int lane = tid & 63;
  const int wid = tid >> 6;
  const int wr = wid >> 2, wc = wid & 3;
  const int l15 = lane & 15, l4 = lane >> 4;
  const int swz = (lane & 7) << 4;            // read-side XOR (row&7)<<4, row&7==lane&7

  const int cpx = gridDim.x >> 3;             // bijective XCD swizzle (nwg%8==0)
  const int orig = (blockIdx.x & 7) * cpx + (blockIdx.x >> 3);
  const int colt = orig & ((1 << nbxl) - 1);
  const int rowt = orig >> nbxl;
  const int row0 = rowt << 8, col0 = colt << 8;

  f32x4 acc[8][4];
  #pragma unroll
  for (int m = 0; m < 8; ++m)
    #pragma unroll
    for (int n = 0; n < 4; ++n) acc[m][n] = (f32x4){0.f, 0.f, 0.f, 0.f};

  // staging geometry: issue c covers rows [c*64, c*64+64); thread -> (srow8, chunk)
  const int srow8 = wid * 8 + (lane >> 3);            // 0..63
  const int csw = ((lane & 7) ^ (lane >> 3)) << 3;    // inverse-swizzled k-chunk (elems)
  const ushort_t* Ag = A + (size_t)(row0 + srow8) * K + csw;
  const ushort_t* Bg = Bw + (size_t)(col0 + srow8) * K + csw;
  const int lbase = wid << 10;                        // wave-uniform LDS byte base

  auto stageA = [&](int kt, int nx) {
    char* dst = smem + (nx << 15) + lbase;
    const ushort_t* src = Ag + kt * 64;
    #pragma unroll
    for (int c = 0; c < 4; ++c)
      gload16((ushort_t*)(dst + c * 8192), src + (size_t)c * 64 * K);
  };
  auto stageB = [&](int kt, int nx) {
    char* dst = smem + 65536 + (nx << 15) + lbase;
    const ushort_t* src = Bg + kt * 64;
    #pragma unroll
    for (int c = 0; c < 4; ++c)
      gload16((ushort_t*)(dst + c * 8192), src + (size_t)c * 64 * K);
  };

  short8 a[8], b0[4], b1[4];
  // per-ks loaders: a[ks*4+mm], b[ks*2+nn]
  auto lda_ks = [&](int cur, int mh, int ks) {
    const char* Ab = smem + (cur << 15);
    #pragma unroll
    for (int mm = 0; mm < 4; ++mm) {
      int ar = wr * 128 + (mh * 4 + mm) * 16 + l15;
      a[ks * 4 + mm] = *(const short8*)(Ab + ar * 128 + ((ks * 64 + l4 * 16) ^ swz));
    }
  };
  auto ldb_ks = [&](short8* bb, int cur, int nh, int ks) {
    const char* Bb = smem + 65536 + (cur << 15);
    #pragma unroll
    for (int nn = 0; nn < 2; ++nn) {
      int br = wc * 64 + (nh * 2 + nn) * 16 + l15;
      bb[ks * 2 + nn] = *(const short8*)(Bb + br * 128 + ((ks * 64 + l4 * 16) ^ swz));
    }
  };
  auto mfma8 = [&](int mh, int nh, int ks, const short8* bb) {
    __builtin_amdgcn_s_setprio(1);
    #pragma unroll
    for (int mm = 0; mm < 4; ++mm)
      #pragma unroll
      for (int nn = 0; nn < 2; ++nn)
        acc[mh * 4 + mm][nh * 2 + nn] = __builtin_amdgcn_mfma_f32_16x16x32_bf16(
            a[ks * 4 + mm], bb[ks * 2 + nn], acc[mh * 4 + mm][nh * 2 + nn], 0, 0, 0);
    __builtin_amdgcn_s_setprio(0);
  };

  // prologue: stage tile 0 into buf 0, drain, sync
  stageA(0, 0);
  stageB(0, 0);
  asm volatile("s_waitcnt vmcnt(0)" ::: "memory");
  __builtin_amdgcn_s_barrier();
  __builtin_amdgcn_sched_barrier(0);

  const int nk = K >> 6;
  for (int t = 0; t < nk; ++t) {
    const int cur = t & 1, nxt = cur ^ 1;
    const int kst = (t + 1 < nk) ? t + 1 : 0;   // dummy re-stage at tail (harmless)
    // ph0: reads ordered per-ks so first MFMA cluster waits only 6 reads
    lda_ks(cur, 0, 0);
    ldb_ks(b0, cur, 0, 0);
    lda_ks(cur, 0, 1);
    ldb_ks(b0, cur, 0, 1);
    stageA(kst, nxt);
    __builtin_amdgcn_s_barrier();
    mfma8(0, 0, 0, b0);
    mfma8(0, 0, 1, b0);
    // ph1: read B-nh1 per-ks ; stage next B
    ldb_ks(b1, cur, 1, 0);
    ldb_ks(b1, cur, 1, 1);
    stageB(kst, nxt);
    __builtin_amdgcn_s_barrier();
    mfma8(0, 1, 0, b1);
    mfma8(0, 1, 1, b1);
    // ph2: read A-mh1 per-ks ; MFMA both remaining quadrants
    lda_ks(cur, 1, 0);
    lda_ks(cur, 1, 1);
    __builtin_amdgcn_s_barrier();
    mfma8(1, 1, 0, b1);
    mfma8(1, 1, 1, b1);
    mfma8(1, 0, 0, b0);
    mfma8(1, 0, 1, b0);
    // boundary: next tile resident (loads are 2-3 phases old), swap buffers
    asm volatile("s_waitcnt vmcnt(0)" ::: "memory");
    __builtin_amdgcn_s_barrier();
    __builtin_amdgcn_sched_barrier(0);
  }

  // epilogue: store bf16 C + per-column partial stats (transposed [col][256])
  const float alpha = alphas[layer];
  float csum[4], csq[4];
  #pragma unroll
  for (int n = 0; n < 4; ++n) { csum[n] = 0.f; csq[n] = 0.f; }
  #pragma unroll
  for (int m = 0; m < 8; ++m) {
    const int rbase = row0 + wr * 128 + m * 16 + l4 * 4;
    #pragma unroll
    for (int n = 0; n < 4; ++n) {
      const int col = col0 + wc * 64 + n * 16 + l15;
      #pragma unroll
      for (int r = 0; r < 4; ++r) {
        ushort_t ub = f2bf(acc[m][n][r] * alpha);
        C[(size_t)(rbase + r) * N + col] = ub;
        float vv = bf2f(ub);
        csum[n] += vv;
        csq[n] += vv * vv;
      }
    }
  }
  #pragma unroll
  for (int n = 0; n < 4; ++n) {
    csum[n] += __shfl_xor(csum[n], 16);
    csum[n] += __shfl_xor(csum[n], 32);
    csq[n]  += __shfl_xor(csq[n], 16);
    csq[n]  += __shfl_xor(csq[n], 32);
  }
  if (l4 == 0) {
    const int prow = rowt * 2 + wr;      // 256 partials per column
    #pragma unroll
    for (int n = 0; n < 4; ++n) {
      const int col = col0 + wc * 64 + n * 16 + l15;
      psum[(size_t)col * 256 + prow] = csum[n];
      psq [(size_t)col * 256 + prow] = csq[n];
    }
  }
}

// ---------------- 128x128-tile GEMM (layer 3: N=256 keeps full-chip grid) -----------
__global__ __launch_bounds__(256, 3) void k_gemm_bt(
    const ushort_t* __restrict__ A, const ushort_t* __restrict__ Bw,
    ushort_t* __restrict__ C, const float* __restrict__ alphas, int layer,
    float* __restrict__ psum, float* __restrict__ psq,
    int N, int K, int nbxl) {
  __shared__ ushort_t As[8192];   // [128][64] linear
  __shared__ ushort_t Bs[8192];
  const int tid = threadIdx.x;
  const int lane = tid & 63;
  const int wv = tid >> 6;
  const int wr = (tid >> 7) & 1;
  const int wc = (tid >> 6) & 1;
  const int l15 = lane & 15, l4 = lane >> 4;

  const int cpx = gridDim.x >> 3;
  const int orig = (blockIdx.x & 7) * cpx + (blockIdx.x >> 3);
  const int colt = orig & ((1 << nbxl) - 1);
  const int rowt = orig >> nbxl;
  const int row0 = rowt << 7, col0 = colt << 7;

  f32x4 acc[4][4];
  #pragma unroll
  for (int m = 0; m < 4; ++m)
    #pragma unroll
    for (int n = 0; n < 4; ++n) acc[m][n] = (f32x4){0.f, 0.f, 0.f, 0.f};

  const int srow = lane >> 3;
  const int sk = (lane & 7) << 3;
  const ushort_t* Ag = A + (size_t)(row0 + wv * 32 + srow) * K + sk;
  const ushort_t* Bg = Bw + (size_t)(col0 + wv * 32 + srow) * K + sk;
  ushort_t* Asw = As + wv * 32 * 64;
  ushort_t* Bsw = Bs + wv * 32 * 64;
  const size_t r8 = (size_t)8 * K;

  const int nk = K >> 6;
  for (int kt = 0; kt < nk; ++kt) {
    __syncthreads();
    const ushort_t* Agk = Ag + kt * 64;
    const ushort_t* Bgk = Bg + kt * 64;
    #pragma unroll
    for (int c = 0; c < 4; ++c) {
      gload16(Asw + c * 512, Agk + c * r8);
      gload16(Bsw + c * 512, Bgk + c * r8);
    }
    __syncthreads();
    #pragma unroll
    for (int ks = 0; ks < 2; ++ks) {
      short8 af[4], bfv[4];
      #pragma unroll
      for (int m = 0; m < 4; ++m)
        af[m] = *(const short8*)(As + (wr * 64 + m * 16 + l15) * 64 + ks * 32 + l4 * 8);
      #pragma unroll
      for (int n = 0; n < 4; ++n)
        bfv[n] = *(const short8*)(Bs + (wc * 64 + n * 16 + l15) * 64 + ks * 32 + l4 * 8);
      #pragma unroll
      for (int m = 0; m < 4; ++m)
        #pragma unroll
        for (int n = 0; n < 4; ++n)
          acc[m][n] = __builtin_amdgcn_mfma_f32_16x16x32_bf16(af[m], bfv[n], acc[m][n], 0, 0, 0);
    }
  }

  const float alpha = alphas[layer];
  float csum[4], csq[4];
  #pragma unroll
  for (int n = 0; n < 4; ++n) { csum[n] = 0.f; csq[n] = 0.f; }
  #pragma unroll
  for (int m = 0; m < 4; ++m) {
    const int rbase = row0 + wr * 64 + m * 16 + l4 * 4;
    #pragma unroll
    for (int n = 0; n < 4; ++n) {
      const int col = col0 + wc * 64 + n * 16 + l15;
      #pragma unroll
      for (int r = 0; r < 4; ++r) {
        ushort_t ub = f2bf(acc[m][n][r] * alpha);
        C[(size_t)(rbase + r) * N + col] = ub;
        float vv = bf2f(ub);
        csum[n] += vv;
        csq[n] += vv * vv;
      }
    }
  }
  #pragma unroll
  for (int n = 0; n < 4; ++n) {
    csum[n] += __shfl_xor(csum[n], 16);
    csum[n] += __shfl_xor(csum[n], 32);
    csq[n]  += __shfl_xor(csq[n], 16);
    csq[n]  += __shfl_xor(csq[n], 32);
  }
  if (l4 == 0) {
    const int prow = rowt * 2 + wr;      // 512 partials per column
    #pragma unroll
    for (int n = 0; n < 4; ++n) {
      const int col = col0 + wc * 64 + n * 16 + l15;
      psum[(size_t)col * 512 + prow] = csum[n];
      psq [(size_t)col * 512 + prow] = csq[n];
    }
  }
}

// ------- fold BN: S = g/sqrt(var+eps), B = b - mean*S. One wave per feature. -------
// psum/psq are [N][P]; coalesced float4 loads + 64-lane shuffle tree. Grid = N/4.
__global__ void k_bn_fin(const float* __restrict__ psum, const float* __restrict__ psq,
                         const float* __restrict__ g, const float* __restrict__ bb,
                         int N, int P, float* __restrict__ SB) {
  int lane = threadIdx.x & 63;
  int f = blockIdx.x * 4 + (threadIdx.x >> 6);
  const float4v* ps = (const float4v*)(psum + (size_t)f * P);
  const float4v* pq = (const float4v*)(psq  + (size_t)f * P);
  float s = 0.f, q = 0.f;
  for (int i = lane; i < (P >> 2); i += 64) {
    float4v a = ps[i], c = pq[i];
    s += (a[0] + a[1]) + (a[2] + a[3]);
    q += (c[0] + c[1]) + (c[2] + c[3]);
  }
  #pragma unroll
  for (int off = 32; off > 0; off >>= 1) {
    s += __shfl_xor(s, off);
    q += __shfl_xor(q, off);
  }
  if (lane == 0) {
    float mean = s * (1.f / 32768.f);
    float var  = q * (1.f / 32768.f) - mean * mean;   // biased, matches torch/jnp
    float Sv = g[f] / sqrtf(var + 1e-5f);
    SB[f] = Sv;
    SB[N + f] = bb[f] - mean * Sv;
  }
}

// ---------------- in-place normalize + ReLU (bf16) ----------------
__global__ void k_bn_norm(ushort_t* __restrict__ Y, const float* __restrict__ SB, int N) {
  size_t e0 = ((size_t)blockIdx.x * 256 + threadIdx.x) * 8;
  int f0 = (int)(e0 & (size_t)(N - 1));
  ushort8 v = *(const ushort8*)(Y + e0);
  const float4v* Sp = (const float4v*)(SB + f0);
  const float4v* Bp = (const float4v*)(SB + N + f0);
  float4v S0 = Sp[0], S1 = Sp[1], B0 = Bp[0], B1 = Bp[1];
  ushort8 o;
  #pragma unroll
  for (int j = 0; j < 4; ++j) {
    float h = fmaxf(bf2f(v[j]) * S0[j] + B0[j], 0.f);
    o[j] = f2bf(h);
  }
  #pragma unroll
  for (int j = 0; j < 4; ++j) {
    float h = fmaxf(bf2f(v[4 + j]) * S1[j] + B1[j], 0.f);
    o[4 + j] = f2bf(h);
  }
  *(ushort8*)(Y + e0) = o;
}

// -------- final layer: out = alpha4 * (relu(bn3(y3)) @ t4^T); norm3 fused in --------
__global__ void k_final(const ushort_t* __restrict__ H, const ushort_t* __restrict__ W4,
                        const float* __restrict__ alphas, const float* __restrict__ SB,
                        float* __restrict__ out) {
  int lane = threadIdx.x & 63, wid = threadIdx.x >> 6;
  int row = blockIdx.x * 4 + wid;
  float a4 = alphas[3];
  ushort4v hv = *(const ushort4v*)(H + (size_t)row * 256 + lane * 4);
  float4v S = *(const float4v*)(SB + lane * 4);
  float4v Bv = *(const float4v*)(SB + 256 + lane * 4);
  float hf[4];
  #pragma unroll
  for (int j = 0; j < 4; ++j)
    hf[j] = fmaxf(bf2f(hv[j]) * S[j] + Bv[j], 0.f);   // BN3 + ReLU fused
  float acc[10];
  #pragma unroll
  for (int c = 0; c < 10; ++c) {
    ushort4v wv = *(const ushort4v*)(W4 + c * 256 + lane * 4);
    acc[c] = hf[0] * bf2f(wv[0]) + hf[1] * bf2f(wv[1]) +
             hf[2] * bf2f(wv[2]) + hf[3] * bf2f(wv[3]);
  }
  #pragma unroll
  for (int c = 0; c < 10; ++c) {
    #pragma unroll
    for (int off = 32; off > 0; off >>= 1) acc[c] += __shfl_xor(acc[c], off);
  }
  if (lane < 10) {
    float v = 0.f;
    #pragma unroll
    for (int c = 0; c < 10; ++c)
      if (lane == c) v = acc[c];
    out[(size_t)row * 10 + lane] = v * a4;
  }
}

// =====================================================================================
extern "C" void kernel_launch(void* const* d_in, const int* in_sizes, int n_in,
                              void* d_out, int out_size, void* d_ws, size_t ws_size,
                              hipStream_t stream) {
  const float* x  = (const float*)d_in[0];
  const float* w1 = (const float*)d_in[1];
  const float* w2 = (const float*)d_in[2];
  const float* w3 = (const float*)d_in[3];
  const float* w4 = (const float*)d_in[4];
  const float* g1 = (const float*)d_in[5];
  const float* b1 = (const float*)d_in[6];
  const float* g2 = (const float*)d_in[7];
  const float* b2 = (const float*)d_in[8];
  const float* g3 = (const float*)d_in[9];
  const float* b3 = (const float*)d_in[10];
  float* out = (float*)d_out;

  // workspace layout (~130 MB, all offsets 256B-aligned; xq aliased for y2)
  char* ws = (char*)d_ws;
  float* alphas   = (float*)(ws + 0);
  float* apart    = (float*)(ws + 256);
  float* SB1      = (float*)(ws + 4096);                 // 2*1024 f32
  float* SB2      = (float*)(ws + 16384);                // 2*512 f32
  float* SB3      = (float*)(ws + 24576);                // 2*256 f32
  float* psum     = (float*)(ws + 32768);                // [N<=1024][<=512] f32 (2 MB)
  float* psq      = (float*)(ws + 2129920);              // 2 MB
  ushort_t* wq1   = (ushort_t*)(ws + 4227072);           // 1024x832
  ushort_t* wq2   = (ushort_t*)(ws + 5931008);           // 512x1024
  ushort_t* wq3   = (ushort_t*)(ws + 6979584);           // 256x512
  ushort_t* wq4   = (ushort_t*)(ws + 7241728);           // 10x256
  ushort_t* xq    = (ushort_t*)(ws + 7246848);           // 32768x832 (54.5 MB)
  ushort_t* y2    = xq;                                  // alias: xq dead after GEMM1
  ushort_t* y3    = (ushort_t*)(ws + 7246848 + 54525952);  // 32768x256 (16.8 MB)
  ushort_t* y1    = (ushort_t*)(ws + 78643200);          // 32768x1024 (67 MB)

  dim3 blk(256);

  k_abs_partial<<<dim3(64, 4), blk, 0, stream>>>(w1, w2, w3, w4, apart);
  k_alpha_fin<<<1, blk, 0, stream>>>(apart, alphas);
  k_quantize<<<dim3(512, 4), blk, 0, stream>>>(w1, w2, w3, w4, wq1, wq2, wq3, wq4, alphas);
  k_convert_x<<<13312, blk, 0, stream>>>(x, xq);

  // layer 1: 32768 x 1024, K = 832; 256^2 tiles -> 128x4 = 512 blocks (nbxl=2)
  k_gemm256<<<512, 512, 0, stream>>>(xq, wq1, y1, alphas, 0, psum, psq, 1024, 832, 2);
  k_bn_fin<<<256, blk, 0, stream>>>(psum, psq, g1, b1, 1024, 256, SB1);
  k_bn_norm<<<16384, blk, 0, stream>>>(y1, SB1, 1024);

  // layer 2: 32768 x 512, K = 1024; 128x2 = 256 blocks (nbxl=1)
  k_gemm256<<<256, 512, 0, stream>>>(y1, wq2, y2, alphas, 1, psum, psq, 512, 1024, 1);
  k_bn_fin<<<128, blk, 0, stream>>>(psum, psq, g2, b2, 512, 256, SB2);
  k_bn_norm<<<8192, blk, 0, stream>>>(y2, SB2, 512);

  // layer 3: 32768 x 256, K = 512; keep 128^2 kernel (512 blocks, full chip)
  k_gemm_bt<<<512, blk, 0, stream>>>(y2, wq3, y3, alphas, 2, psum, psq, 256, 512, 1);
  k_bn_fin<<<64, blk, 0, stream>>>(psum, psq, g3, b3, 256, 512, SB3);
  // layer-3 normalize+ReLU fused into k_final

  // layer 4: 32768 x 10, K = 256 (memory-bound GEMV, BN3+ReLU fused)
  k_final<<<8192, blk, 0, stream>>>(y3, wq4, alphas, SB3, out);
}